// Round 20
// baseline (29.068 us; speedup 1.0000x reference)
//
#include <hip/hip_runtime.h>
#include <hip/hip_bf16.h>

#define B_   16
#define NC_  1024
#define NQ_  128
#define D_   512
#define NKT  8        // K-tiles: 512/64

typedef __attribute__((ext_vector_type(8))) short bf16x8;
typedef __attribute__((ext_vector_type(4))) float f32x4;

// fp32 -> bf16 RTNE
__device__ __forceinline__ short f2bf(float x) {
    return __builtin_bit_cast(short, __float2bfloat16(x));
}
// bf16 -> fp32 (exact)
__device__ __forceinline__ float bf2f(short s) {
    unsigned u = ((unsigned)(unsigned short)s) << 16;
    return __builtin_bit_cast(float, u);
}

// R20: R19 verbatim + ONE change: __launch_bounds__(512, 8) -> VGPR cap 64 ->
// 8 waves/SIMD (4 blocks/CU; LDS 4x35.5KB = 142KB < 160KB fits). R19 was at
// ~70 VGPR / 4 waves/SIMD; if the allocator fits 64 without spill, TLP over
// the latency stalls doubles. If it spills into the WRITE path, this regresses
// and R19 stands as final.
__global__ __launch_bounds__(512, 8) void sim_kernel(
    const float* __restrict__ c, const float* __restrict__ q,
    const float* __restrict__ kern, const float* __restrict__ bias_p,
    float* __restrict__ out)
{
    __shared__ __align__(16) char  lds[2][16384];  // per buf: A@0 | B@8192
    __shared__ __align__(16) short wl[1536];       // bf16: w_c | w_q | w_cq
    __shared__ __align__(16) float ctl[64];

    const int bid   = blockIdx.x;
    const int b     = ((bid & 7) << 1) | (bid >> 8);   // XCD-affine batch (bijective)
    const int inner = (bid >> 3) & 31;
    const int mt    = inner >> 1;                      // 16 M-tiles of 64 rows
    const int nb    = inner & 1;                       // 2 N-halves of 64 cols
    const int tid   = threadIdx.x;
    const int lane  = tid & 63;
    const int wid   = tid >> 6;                        // 0..7
    const int wm    = wid >> 2, wn = wid & 3;          // 2x4 wave grid; wave tile 32x16
    const int rif   = lane & 15;
    const int kg    = lane >> 4;

    // ---- weights -> LDS bf16 (once; 192 threads x 8) ----
    if (tid < 192) {
        const float* s = kern + tid * 8;
        f32x4 v0 = *(const f32x4*)s;
        f32x4 v1 = *(const f32x4*)(s + 4);
        bf16x8 o;
        o[0]=f2bf(v0[0]); o[1]=f2bf(v0[1]); o[2]=f2bf(v0[2]); o[3]=f2bf(v0[3]);
        o[4]=f2bf(v1[0]); o[5]=f2bf(v1[1]); o[6]=f2bf(v1[2]); o[7]=f2bf(v1[3]);
        *(bf16x8*)&wl[tid * 8] = o;
    }

    // ---- staging: 512 threads; A row ar=tid>>3, B row bj=ar, col slice (tid&7)*8 ----
    const int ar  = tid >> 3;
    const int acs = (tid & 7) * 8;
    const float* ag = c + (size_t)(b * NC_ + mt * 64 + ar) * D_ + acs;
    const int aw = ar * 128 + ((acs * 2) ^ ((ar & 7) << 4));

    const int bj  = ar;
    const float* bg = q + (size_t)(b * NQ_ + nb * 64 + bj) * D_ + acs;
    const int bw = 8192 + bj * 128 + ((acs * 2) ^ ((bj & 7) << 4));

    f32x4 sa[2][2], sb[2][2];          // 2 tiles in flight, 8 floats each side
    float cta = 0.f;
    f32x4 acc00 = {}, acc10 = {};      // wave tile 32x16
    f32x4 acc_q0 = {};                 // D[i][j] = qt_j (broadcast-A MFMA, raw B)

#define ISSUE(T)                                                   \
    do { const int s_ = (T) & 1;                                   \
        sa[s_][0] = *(const f32x4*)(ag + (T) * 64);                \
        sa[s_][1] = *(const f32x4*)(ag + (T) * 64 + 4);            \
        sb[s_][0] = *(const f32x4*)(bg + (T) * 64);                \
        sb[s_][1] = *(const f32x4*)(bg + (T) * 64 + 4);            \
    } while (0)

#define WRITE(T)                                                               \
    do { const int s_ = (T) & 1; char* Lw = &lds[s_][0];                       \
        bf16x8 wcq = *(const bf16x8*)&wl[1024 + (T) * 64 + acs];               \
        bf16x8 wc8 = *(const bf16x8*)&wl[       (T) * 64 + acs];               \
        bf16x8 oa, ob;                                                         \
        _Pragma("unroll")                                                      \
        for (int e = 0; e < 8; ++e) {                                          \
            float x = sa[s_][e >> 2][e & 3];                                   \
            oa[e] = f2bf(x * bf2f(wcq[e]));                                    \
            cta += x * bf2f(wc8[e]);                                           \
            ob[e] = f2bf(sb[s_][e >> 2][e & 3]);                               \
        }                                                                      \
        *(bf16x8*)(Lw + aw) = oa;                                              \
        *(bf16x8*)(Lw + bw) = ob;                                              \
    } while (0)

#define COMPUTE(T)                                                                                   \
    do { const char* L = &lds[(T) & 1][0];                                                           \
        _Pragma("unroll")                                                                            \
        for (int kk = 0; kk < 2; ++kk) {                                                             \
            const int ks = kk * 64 + kg * 16;                                                        \
            bf16x8 af0, af1, bf0, wqf;                                                               \
            { int r = wm*32 + rif;      af0 = *(const bf16x8*)(L + r*128 + (ks ^ ((r & 7) << 4))); } \
            { int r = wm*32 + 16 + rif; af1 = *(const bf16x8*)(L + r*128 + (ks ^ ((r & 7) << 4))); } \
            { int j = wn*16 + rif;      bf0 = *(const bf16x8*)(L + 8192 + j*128 + (ks ^ ((j & 7) << 4))); } \
            wqf = *(const bf16x8*)&wl[512 + (T) * 64 + kk * 32 + kg * 8];                            \
            acc00 = __builtin_amdgcn_mfma_f32_16x16x32_bf16(af0, bf0, acc00, 0, 0, 0);               \
            acc10 = __builtin_amdgcn_mfma_f32_16x16x32_bf16(af1, bf0, acc10, 0, 0, 0);               \
            acc_q0 = __builtin_amdgcn_mfma_f32_16x16x32_bf16(wqf, bf0, acc_q0, 0, 0, 0);             \
        }                                                                                            \
    } while (0)

    // ---- prologue ----
    ISSUE(0); ISSUE(1);
    asm volatile("s_waitcnt lgkmcnt(0)" ::: "memory");
    __builtin_amdgcn_sched_barrier(0);
    __builtin_amdgcn_s_barrier();
    WRITE(0);
    asm volatile("s_waitcnt lgkmcnt(0)" ::: "memory");
    __builtin_amdgcn_sched_barrier(0);
    __builtin_amdgcn_s_barrier();

    #pragma unroll
    for (int kt = 0; kt < NKT; ++kt) {
        if (kt + 2 < NKT) ISSUE(kt + 2);
        __builtin_amdgcn_sched_barrier(0);
        COMPUTE(kt);
        if (kt + 1 < NKT) {
            WRITE(kt + 1);
            asm volatile("s_waitcnt lgkmcnt(0)" ::: "memory");
            __builtin_amdgcn_sched_barrier(0);
            __builtin_amdgcn_s_barrier();
        }
    }
#undef ISSUE
#undef WRITE
#undef COMPUTE

    // ---- ct reduction: 8 threads (tid&7) share row ar ----
    cta += __shfl_xor(cta, 1); cta += __shfl_xor(cta, 2); cta += __shfl_xor(cta, 4);
    if ((tid & 7) == 0) ctl[ar] = cta;
    asm volatile("s_waitcnt lgkmcnt(0)" ::: "memory");
    __builtin_amdgcn_sched_barrier(0);
    __builtin_amdgcn_s_barrier();

    // ---- epilogue: out = cq + ct + qt + bias ----
    const float bias = *bias_p;
    const float qt0 = acc_q0[0] + bias;     // all regs equal qt_j (j = wn*16+rif)
    #pragma unroll
    for (int mf = 0; mf < 2; ++mf) {
        f32x4 ctv = *(const f32x4*)&ctl[wm * 32 + mf * 16 + kg * 4];
        float* o = out + ((size_t)(b * NC_ + mt * 64 + wm * 32 + mf * 16 + kg * 4)) * NQ_
                 + nb * 64 + wn * 16 + rif;
        const f32x4 a0 = mf ? acc10 : acc00;
        #pragma unroll
        for (int r = 0; r < 4; ++r)
            o[(size_t)r * NQ_] = a0[r] + ctv[r] + qt0;
    }
}

extern "C" void kernel_launch(void* const* d_in, const int* in_sizes, int n_in,
                              void* d_out, int out_size, void* d_ws, size_t ws_size,
                              hipStream_t stream) {
    const float* c    = (const float*)d_in[0];
    const float* q    = (const float*)d_in[1];
    const float* kern = (const float*)d_in[2];
    const float* bias = (const float*)d_in[3];
    float* out = (float*)d_out;

    // Grid 512 blocks x 512 threads (8 waves/block; launch config matches kernel geometry).
    sim_kernel<<<512, 512, 0, stream>>>(c, q, kern, bias, out);
}

// Round 21
// 15.119 us; speedup vs baseline: 1.9226x; 1.9226x over previous
//
#include <hip/hip_runtime.h>
#include <hip/hip_bf16.h>

#define B_   16
#define NC_  1024
#define NQ_  128
#define D_   512
#define NKT  8        // K-tiles: 512/64

typedef __attribute__((ext_vector_type(8))) short bf16x8;
typedef __attribute__((ext_vector_type(4))) float f32x4;

// fp32 -> bf16 RTNE
__device__ __forceinline__ short f2bf(float x) {
    return __builtin_bit_cast(short, __float2bfloat16(x));
}
// bf16 -> fp32 (exact)
__device__ __forceinline__ float bf2f(short s) {
    unsigned u = ((unsigned)(unsigned short)s) << 16;
    return __builtin_bit_cast(float, u);
}

// R21 = R19 verbatim (REVERT of R20's launch_bounds(512,8), which spilled:
// VGPR_Count 32-reported/scratch-bound, 57MB spill writes, 29us).
// R19 = session best, 15.29us:
//  - single fused kernel, 64x64 tile, 8 waves (2Mx4N, wave tile 32x16), grid 512
//  - A = bf16(c*w_cq) fold-on-A; B = bf16(q) raw
//  - ct_i = VALU side-sum on raw A during WRITE; qt_j = broadcast-MFMA on raw B
//  - ring-2 LDS, ISSUE(kt+2) 2-deep lookahead, raw s_barrier + lgkmcnt(0) only
//  - XOR swizzle byte^=((row&7)<<4); XCD-affine block decode
__global__ __launch_bounds__(512, 4) void sim_kernel(
    const float* __restrict__ c, const float* __restrict__ q,
    const float* __restrict__ kern, const float* __restrict__ bias_p,
    float* __restrict__ out)
{
    __shared__ __align__(16) char  lds[2][16384];  // per buf: A@0 | B@8192
    __shared__ __align__(16) short wl[1536];       // bf16: w_c | w_q | w_cq
    __shared__ __align__(16) float ctl[64];

    const int bid   = blockIdx.x;
    const int b     = ((bid & 7) << 1) | (bid >> 8);   // XCD-affine batch (bijective)
    const int inner = (bid >> 3) & 31;
    const int mt    = inner >> 1;                      // 16 M-tiles of 64 rows
    const int nb    = inner & 1;                       // 2 N-halves of 64 cols
    const int tid   = threadIdx.x;
    const int lane  = tid & 63;
    const int wid   = tid >> 6;                        // 0..7
    const int wm    = wid >> 2, wn = wid & 3;          // 2x4 wave grid; wave tile 32x16
    const int rif   = lane & 15;
    const int kg    = lane >> 4;

    // ---- weights -> LDS bf16 (once; 192 threads x 8) ----
    if (tid < 192) {
        const float* s = kern + tid * 8;
        f32x4 v0 = *(const f32x4*)s;
        f32x4 v1 = *(const f32x4*)(s + 4);
        bf16x8 o;
        o[0]=f2bf(v0[0]); o[1]=f2bf(v0[1]); o[2]=f2bf(v0[2]); o[3]=f2bf(v0[3]);
        o[4]=f2bf(v1[0]); o[5]=f2bf(v1[1]); o[6]=f2bf(v1[2]); o[7]=f2bf(v1[3]);
        *(bf16x8*)&wl[tid * 8] = o;
    }

    // ---- staging: 512 threads; A row ar=tid>>3, B row bj=ar, col slice (tid&7)*8 ----
    const int ar  = tid >> 3;
    const int acs = (tid & 7) * 8;
    const float* ag = c + (size_t)(b * NC_ + mt * 64 + ar) * D_ + acs;
    const int aw = ar * 128 + ((acs * 2) ^ ((ar & 7) << 4));

    const int bj  = ar;
    const float* bg = q + (size_t)(b * NQ_ + nb * 64 + bj) * D_ + acs;
    const int bw = 8192 + bj * 128 + ((acs * 2) ^ ((bj & 7) << 4));

    f32x4 sa[2][2], sb[2][2];          // 2 tiles in flight, 8 floats each side
    float cta = 0.f;
    f32x4 acc00 = {}, acc10 = {};      // wave tile 32x16
    f32x4 acc_q0 = {};                 // D[i][j] = qt_j (broadcast-A MFMA, raw B)

#define ISSUE(T)                                                   \
    do { const int s_ = (T) & 1;                                   \
        sa[s_][0] = *(const f32x4*)(ag + (T) * 64);                \
        sa[s_][1] = *(const f32x4*)(ag + (T) * 64 + 4);            \
        sb[s_][0] = *(const f32x4*)(bg + (T) * 64);                \
        sb[s_][1] = *(const f32x4*)(bg + (T) * 64 + 4);            \
    } while (0)

#define WRITE(T)                                                               \
    do { const int s_ = (T) & 1; char* Lw = &lds[s_][0];                       \
        bf16x8 wcq = *(const bf16x8*)&wl[1024 + (T) * 64 + acs];               \
        bf16x8 wc8 = *(const bf16x8*)&wl[       (T) * 64 + acs];               \
        bf16x8 oa, ob;                                                         \
        _Pragma("unroll")                                                      \
        for (int e = 0; e < 8; ++e) {                                          \
            float x = sa[s_][e >> 2][e & 3];                                   \
            oa[e] = f2bf(x * bf2f(wcq[e]));                                    \
            cta += x * bf2f(wc8[e]);                                           \
            ob[e] = f2bf(sb[s_][e >> 2][e & 3]);                               \
        }                                                                      \
        *(bf16x8*)(Lw + aw) = oa;                                              \
        *(bf16x8*)(Lw + bw) = ob;                                              \
    } while (0)

#define COMPUTE(T)                                                                                   \
    do { const char* L = &lds[(T) & 1][0];                                                           \
        _Pragma("unroll")                                                                            \
        for (int kk = 0; kk < 2; ++kk) {                                                             \
            const int ks = kk * 64 + kg * 16;                                                        \
            bf16x8 af0, af1, bf0, wqf;                                                               \
            { int r = wm*32 + rif;      af0 = *(const bf16x8*)(L + r*128 + (ks ^ ((r & 7) << 4))); } \
            { int r = wm*32 + 16 + rif; af1 = *(const bf16x8*)(L + r*128 + (ks ^ ((r & 7) << 4))); } \
            { int j = wn*16 + rif;      bf0 = *(const bf16x8*)(L + 8192 + j*128 + (ks ^ ((j & 7) << 4))); } \
            wqf = *(const bf16x8*)&wl[512 + (T) * 64 + kk * 32 + kg * 8];                            \
            acc00 = __builtin_amdgcn_mfma_f32_16x16x32_bf16(af0, bf0, acc00, 0, 0, 0);               \
            acc10 = __builtin_amdgcn_mfma_f32_16x16x32_bf16(af1, bf0, acc10, 0, 0, 0);               \
            acc_q0 = __builtin_amdgcn_mfma_f32_16x16x32_bf16(wqf, bf0, acc_q0, 0, 0, 0);             \
        }                                                                                            \
    } while (0)

    // ---- prologue ----
    ISSUE(0); ISSUE(1);
    asm volatile("s_waitcnt lgkmcnt(0)" ::: "memory");
    __builtin_amdgcn_sched_barrier(0);
    __builtin_amdgcn_s_barrier();
    WRITE(0);
    asm volatile("s_waitcnt lgkmcnt(0)" ::: "memory");
    __builtin_amdgcn_sched_barrier(0);
    __builtin_amdgcn_s_barrier();

    #pragma unroll
    for (int kt = 0; kt < NKT; ++kt) {
        if (kt + 2 < NKT) ISSUE(kt + 2);
        __builtin_amdgcn_sched_barrier(0);
        COMPUTE(kt);
        if (kt + 1 < NKT) {
            WRITE(kt + 1);
            asm volatile("s_waitcnt lgkmcnt(0)" ::: "memory");
            __builtin_amdgcn_sched_barrier(0);
            __builtin_amdgcn_s_barrier();
        }
    }
#undef ISSUE
#undef WRITE
#undef COMPUTE

    // ---- ct reduction: 8 threads (tid&7) share row ar ----
    cta += __shfl_xor(cta, 1); cta += __shfl_xor(cta, 2); cta += __shfl_xor(cta, 4);
    if ((tid & 7) == 0) ctl[ar] = cta;
    asm volatile("s_waitcnt lgkmcnt(0)" ::: "memory");
    __builtin_amdgcn_sched_barrier(0);
    __builtin_amdgcn_s_barrier();

    // ---- epilogue: out = cq + ct + qt + bias ----
    const float bias = *bias_p;
    const float qt0 = acc_q0[0] + bias;     // all regs equal qt_j (j = wn*16+rif)
    #pragma unroll
    for (int mf = 0; mf < 2; ++mf) {
        f32x4 ctv = *(const f32x4*)&ctl[wm * 32 + mf * 16 + kg * 4];
        float* o = out + ((size_t)(b * NC_ + mt * 64 + wm * 32 + mf * 16 + kg * 4)) * NQ_
                 + nb * 64 + wn * 16 + rif;
        const f32x4 a0 = mf ? acc10 : acc00;
        #pragma unroll
        for (int r = 0; r < 4; ++r)
            o[(size_t)r * NQ_] = a0[r] + ctv[r] + qt0;
    }
}

extern "C" void kernel_launch(void* const* d_in, const int* in_sizes, int n_in,
                              void* d_out, int out_size, void* d_ws, size_t ws_size,
                              hipStream_t stream) {
    const float* c    = (const float*)d_in[0];
    const float* q    = (const float*)d_in[1];
    const float* kern = (const float*)d_in[2];
    const float* bias = (const float*)d_in[3];
    float* out = (float*)d_out;

    // Grid 512 blocks x 512 threads (8 waves/block; launch config matches kernel geometry).
    sim_kernel<<<512, 512, 0, stream>>>(c, q, kern, bias, out);
}